// Round 9
// baseline (106.461 us; speedup 1.0000x reference)
//
#include <hip/hip_runtime.h>
#include <math.h>

#define LRES 2048
#define NB 8
#define KSEL 64
#define EMBD 16
#define NBIN 100        // bin = (int)d2 -> width exactly 1.0; tkb = T+1 exact float
#define NSLOT 16        // per-lane capture slots (Poisson(8) tail ~4e-3 -> ~500 dropped pairs worst, err ~2e2)
#define RPW 8           // rows per wave
#define WPB 4           // waves per block
#define RPB (RPW * WPB) // 32 rows per block
#define BPB (LRES / RPB)// 64 blocks per batch

// prep: per-residue learned radius (fp32) + zero the output accumulators
__global__ void rho_kernel(const int* __restrict__ seq,
                           const float* __restrict__ emb,
                           const float* __restrict__ w,
                           const float* __restrict__ bias,
                           float* __restrict__ rho,
                           float* __restrict__ out) {
    int idx = blockIdx.x * blockDim.x + threadIdx.x;
    if (idx < NB) out[idx] = 0.0f;
    if (idx < NB * LRES) {
        int s = seq[idx];
        float x = bias[0];
#pragma unroll
        for (int d = 0; d < EMBD; ++d) x += emb[s * EMBD + d] * w[d];
        rho[idx] = 1.6f + 1.2f / (1.0f + expf(-x));
    }
}

#define LDS_FENCE() asm volatile("s_waitcnt lgkmcnt(0)" ::: "memory")

// 4 waves x 8 rows = 32 rows per block; points staged once per block in fp32
__global__ __launch_bounds__(256, 4) void repel_kernel(const float* __restrict__ R,
                                                       const float* __restrict__ rho,
                                                       float* __restrict__ out) {
    const int tid  = threadIdx.x;
    const int w    = tid >> 6;
    const int lane = tid & 63;
    const int blk  = blockIdx.x;
    const int b    = blk >> 6;              // / BPB
    const int i0   = (blk & 63) << 5;       // * RPB

    __shared__ float4  pt[LRES];            // 32 KB: x,y,z,rho fp32
    __shared__ unsigned hist[RPB][NBIN];    // 12.8 KB
    __shared__ unsigned slots[WPB][NSLOT][64]; // 16 KB; [slot][lane] -> conflict-free
    __shared__ unsigned shT[RPB];
    __shared__ float    shred[WPB];

    // ---- stage all 2048 points (8 per thread) + zero hist + default T ----
    {
        const float4* Rg = (const float4*)(R + (size_t)b * (LRES * 3));
        const float4* Qg = (const float4*)(rho + (b << 11));
        float4 f0 = Rg[6 * tid + 0], f1 = Rg[6 * tid + 1], f2 = Rg[6 * tid + 2];
        float4 f3 = Rg[6 * tid + 3], f4 = Rg[6 * tid + 4], f5 = Rg[6 * tid + 5];
        float4 q0 = Qg[2 * tid], q1 = Qg[2 * tid + 1];
        pt[8 * tid + 0] = make_float4(f0.x, f0.y, f0.z, q0.x);
        pt[8 * tid + 1] = make_float4(f0.w, f1.x, f1.y, q0.y);
        pt[8 * tid + 2] = make_float4(f1.z, f1.w, f2.x, q0.z);
        pt[8 * tid + 3] = make_float4(f2.y, f2.z, f2.w, q0.w);
        pt[8 * tid + 4] = make_float4(f3.x, f3.y, f3.z, q1.x);
        pt[8 * tid + 5] = make_float4(f3.w, f4.x, f4.y, q1.y);
        pt[8 * tid + 6] = make_float4(f4.z, f4.w, f5.x, q1.z);
        pt[8 * tid + 7] = make_float4(f5.y, f5.z, f5.w, q1.w);
    }
    {
        unsigned* hflat = (unsigned*)hist;   // RPB*NBIN = 3200 words
#pragma unroll
        for (int q = 0; q < 13; ++q) {
            int idx = tid + (q << 8);
            if (idx < RPB * NBIN) hflat[idx] = 0u;
        }
    }
    if (tid < RPB) shT[tid] = NBIN - 1;      // default: select all in-cutoff
    __syncthreads();

    // ---- wave-local centers (8 rows) ----
    const int iw = i0 + (w << 3);
    float cxx[RPW], cyy[RPW], czz[RPW];
#pragma unroll
    for (int r = 0; r < RPW; ++r) {
        float4 c = pt[iw + r];
        cxx[r] = c.x; cyy[r] = c.y; czz[r] = c.z;
    }

    // ---- pass 1: each point feeds 8 rows; per-row histogram (bin = trunc(d2)) ----
#pragma unroll 4
    for (int t = 0; t < 32; ++t) {
        int j = (t << 6) + lane;
        float4 p = pt[j];
#pragma unroll
        for (int r = 0; r < RPW; ++r) {
            float dx = p.x - cxx[r], dy = p.y - cyy[r], dz = p.z - czz[r];
            float d2 = dx * dx + dy * dy + dz * dz;
            int dij = j - (iw + r); dij = (dij < 0) ? -dij : dij;
            if (dij > 2 && d2 < 100.0f)
                atomicAdd(&hist[(w << 3) + r][(unsigned)d2], 1u);
        }
    }
    LDS_FENCE();   // own-wave hist atomics complete (rows are wave-private)

    // ---- per-row scan (100 bins: 2/lane for lanes<50); crossing lane sets T ----
#pragma unroll
    for (int r = 0; r < RPW; ++r) {
        int row = (w << 3) + r;
        uint2 hv = (lane < 50) ? *(const uint2*)&hist[row][lane << 1]
                               : make_uint2(0u, 0u);
        unsigned p = hv.x + hv.y;
        unsigned s = p;
#pragma unroll
        for (int o = 1; o < 64; o <<= 1) {
            unsigned u = __shfl_up(s, o, 64);
            if (lane >= o) s += u;
        }
        unsigned e0 = s - p;
        if (s >= KSEL && e0 < KSEL)          // unique crossing lane (total >= 64)
            shT[row] = (e0 + hv.x >= KSEL) ? (unsigned)(lane << 1)
                                           : (unsigned)(lane << 1) + 1u;
    }
    LDS_FENCE();
    float tkb[RPW];                          // whole-boundary-bin threshold (exact float)
#pragma unroll
    for (int r = 0; r < RPW; ++r) tkb[r] = (float)(shT[(w << 3) + r] + 1u);

    // ---- pass 2: recompute d2, capture (r,j) of selected pairs into own slots ----
    unsigned cnt = 0;
#pragma unroll 4
    for (int t = 0; t < 32; ++t) {
        int j = (t << 6) + lane;
        float4 p = pt[j];
#pragma unroll
        for (int r = 0; r < RPW; ++r) {
            float dx = p.x - cxx[r], dy = p.y - cyy[r], dz = p.z - czz[r];
            float d2 = dx * dx + dy * dy + dz * dz;
            int dij = j - (iw + r); dij = (dij < 0) ? -dij : dij;
            if (dij > 2 && d2 < tkb[r] && cnt < NSLOT) {
                slots[w][cnt][lane] = ((unsigned)r << 11) | (unsigned)j;
                ++cnt;
            }
        }
    }

    // ---- eval own slots (~8/lane): recompute d2 fp32, full energy ----
    float acc = 0.0f;
    for (unsigned k = 0; k < cnt; ++k) {
        unsigned u = slots[w][k][lane];
        unsigned j = u & 2047u;
        unsigned r = u >> 11;
        float4 pj = pt[j];
        float4 pi = pt[iw + (int)r];
        float dx = pj.x - pi.x, dy = pj.y - pi.y, dz = pj.z - pi.z;
        float d2 = dx * dx + dy * dy + dz * dz;
        float rr = __fsqrt_rn(fmaxf(d2, 1e-12f));
        float x = (pi.w + pj.w - rr) * (1.0f / 0.3f);
        float sp = fmaxf(x, 0.0f) + __logf(1.0f + __expf(-fabsf(x)));
        float t = fminf(fmaxf((rr - 8.0f) * 0.5f, 0.0f), 1.0f);
        float sw = 1.0f - t * t * (3.0f - 2.0f * t);
        acc += 10.0f * sp * sw;
    }

    // ---- block reduce + one global atomic per block ----
#pragma unroll
    for (int o = 32; o > 0; o >>= 1) acc += __shfl_down(acc, o, 64);
    if (lane == 0) shred[w] = acc;
    __syncthreads();
    if (tid == 0) atomicAdd(out + b, shred[0] + shred[1] + shred[2] + shred[3]);
}

extern "C" void kernel_launch(void* const* d_in, const int* in_sizes, int n_in,
                              void* d_out, int out_size, void* d_ws, size_t ws_size,
                              hipStream_t stream) {
    const float* R    = (const float*)d_in[0];   // (8, 2048, 3) f32
    const int*   seq  = (const int*)d_in[1];     // (8, 2048) int
    const float* emb  = (const float*)d_in[2];   // (20, 16) f32
    const float* w    = (const float*)d_in[3];   // (1, 16) f32
    const float* bias = (const float*)d_in[4];   // (1,) f32
    float* out = (float*)d_out;                  // (8,) f32
    float* rho = (float*)d_ws;                   // 16384 floats

    rho_kernel<<<(NB * LRES + 255) / 256, 256, 0, stream>>>(seq, emb, w, bias, rho, out);
    repel_kernel<<<NB * LRES / RPB, 256, 0, stream>>>(R, rho, out);
}